// Round 5
// baseline (114.486 us; speedup 1.0000x reference)
//
#include <hip/hip_runtime.h>

// LIF neuron, T=4, decay=0.5, vth=1.0 (soft reset).
// x: (256, 65536) f32, rows grouped as n*T+t. One thread per
// (neuron n = blockIdx.y, float4 column). v carried in registers across t.
// All 4 time-step loads issued up front (MLP); nontemporal hints since
// every byte is touched exactly once.
// NOTE: __builtin_nontemporal_* requires clang native vectors, not
// HIP_vector_type — use ext_vector_type(4) alias.

#define T_STEPS 4
#define DECAY   0.5f
#define VTH     1.0f

typedef float f32x4 __attribute__((ext_vector_type(4)));

__device__ __forceinline__ f32x4 lif_step(f32x4& v, f32x4 xv) {
    v = v * DECAY + xv;                      // elementwise leak + integrate
    f32x4 s;
    s.x = (v.x >= VTH) ? 1.f : 0.f;
    s.y = (v.y >= VTH) ? 1.f : 0.f;
    s.z = (v.z >= VTH) ? 1.f : 0.f;
    s.w = (v.w >= VTH) ? 1.f : 0.f;
    v = v - s * VTH;                         // soft reset
    return s;
}

__global__ __launch_bounds__(256) void lif_kernel(
    const f32x4* __restrict__ x, f32x4* __restrict__ out, int f4_per_row) {
    int f = blockIdx.x * blockDim.x + threadIdx.x;   // float4 column
    int n = blockIdx.y;                              // neuron index

    size_t base = ((size_t)n * T_STEPS) * f4_per_row + f;
    const f32x4* xp = x + base;
    f32x4*       op = out + base;

    // Hoist all 4 loads: 64 B in flight per thread before any compute.
    f32x4 x0 = __builtin_nontemporal_load(xp + (size_t)0 * f4_per_row);
    f32x4 x1 = __builtin_nontemporal_load(xp + (size_t)1 * f4_per_row);
    f32x4 x2 = __builtin_nontemporal_load(xp + (size_t)2 * f4_per_row);
    f32x4 x3 = __builtin_nontemporal_load(xp + (size_t)3 * f4_per_row);

    f32x4 v = (f32x4)(0.f);
    f32x4 s0 = lif_step(v, x0);
    f32x4 s1 = lif_step(v, x1);
    f32x4 s2 = lif_step(v, x2);
    f32x4 s3 = lif_step(v, x3);

    __builtin_nontemporal_store(s0, op + (size_t)0 * f4_per_row);
    __builtin_nontemporal_store(s1, op + (size_t)1 * f4_per_row);
    __builtin_nontemporal_store(s2, op + (size_t)2 * f4_per_row);
    __builtin_nontemporal_store(s3, op + (size_t)3 * f4_per_row);
}

extern "C" void kernel_launch(void* const* d_in, const int* in_sizes, int n_in,
                              void* d_out, int out_size, void* d_ws, size_t ws_size,
                              hipStream_t stream) {
    const float* x = (const float*)d_in[0];
    float* out = (float*)d_out;

    const int B = 256;                 // N*T rows
    const int F = in_sizes[0] / B;     // 65536
    const int N = B / T_STEPS;         // 64
    const int F4 = F / 4;              // 16384 float4 per row

    dim3 block(256);
    dim3 grid(F4 / 256, N);            // (64, 64) blocks

    lif_kernel<<<grid, block, 0, stream>>>(
        (const f32x4*)x, (f32x4*)out, F4);
}

// Round 6
// 108.655 us; speedup vs baseline: 1.0537x; 1.0537x over previous
//
#include <hip/hip_runtime.h>

// LIF neuron, T=4, decay=0.5, vth=1.0 (soft reset).
// x: (256, 65536) f32, rows grouped as n*T+t. One thread per
// (neuron n = blockIdx.y, float4 column). v carried in registers across t.
// All 4 time-step loads issued up front (MLP). Plain (cached) loads/stores:
// harness restores d_in right before launch, so input is L3-warm — NT hints
// regressed 109->114.5 by bypassing that (round-5 A/B).

#define T_STEPS 4
#define DECAY   0.5f
#define VTH     1.0f

typedef float f32x4 __attribute__((ext_vector_type(4)));

__device__ __forceinline__ f32x4 lif_step(f32x4& v, f32x4 xv) {
    v = v * DECAY + xv;                      // elementwise leak + integrate
    f32x4 s;
    s.x = (v.x >= VTH) ? 1.f : 0.f;
    s.y = (v.y >= VTH) ? 1.f : 0.f;
    s.z = (v.z >= VTH) ? 1.f : 0.f;
    s.w = (v.w >= VTH) ? 1.f : 0.f;
    v = v - s * VTH;                         // soft reset
    return s;
}

__global__ __launch_bounds__(256) void lif_kernel(
    const f32x4* __restrict__ x, f32x4* __restrict__ out, int f4_per_row) {
    int f = blockIdx.x * blockDim.x + threadIdx.x;   // float4 column
    int n = blockIdx.y;                              // neuron index

    size_t base = ((size_t)n * T_STEPS) * f4_per_row + f;
    const f32x4* xp = x + base;
    f32x4*       op = out + base;

    // Hoist all 4 loads: 64 B in flight per thread before any compute.
    f32x4 x0 = xp[(size_t)0 * f4_per_row];
    f32x4 x1 = xp[(size_t)1 * f4_per_row];
    f32x4 x2 = xp[(size_t)2 * f4_per_row];
    f32x4 x3 = xp[(size_t)3 * f4_per_row];

    f32x4 v = (f32x4)(0.f);
    f32x4 s0 = lif_step(v, x0);
    f32x4 s1 = lif_step(v, x1);
    f32x4 s2 = lif_step(v, x2);
    f32x4 s3 = lif_step(v, x3);

    op[(size_t)0 * f4_per_row] = s0;
    op[(size_t)1 * f4_per_row] = s1;
    op[(size_t)2 * f4_per_row] = s2;
    op[(size_t)3 * f4_per_row] = s3;
}

extern "C" void kernel_launch(void* const* d_in, const int* in_sizes, int n_in,
                              void* d_out, int out_size, void* d_ws, size_t ws_size,
                              hipStream_t stream) {
    const float* x = (const float*)d_in[0];
    float* out = (float*)d_out;

    const int B = 256;                 // N*T rows
    const int F = in_sizes[0] / B;     // 65536
    const int N = B / T_STEPS;         // 64
    const int F4 = F / 4;              // 16384 float4 per row

    dim3 block(256);
    dim3 grid(F4 / 256, N);            // (64, 64) blocks

    lif_kernel<<<grid, block, 0, stream>>>(
        (const f32x4*)x, (f32x4*)out, F4);
}

// Round 7
// 105.218 us; speedup vs baseline: 1.0881x; 1.0327x over previous
//
#include <hip/hip_runtime.h>

// LIF neuron, T=4, decay=0.5, vth=1.0 (soft reset).
// x: (256, 65536) f32, rows grouped as n*T+t. One thread per
// (neuron n = blockIdx.y, float4 column). v carried in registers across t.
// A/B ledger: plain loads+stores = 108.65 us; NT loads+stores = 114.5 us
// (NT loads harmful: d_in is HBM-cold anyway after the 256MiB ws-poison
// evicts L3, and NT forfeits nothing but adds no benefit on loads).
// This round: NT STORES ONLY — output is written once, never read;
// bypassing L2 write-allocate avoids dirty-line eviction churn.

#define T_STEPS 4
#define DECAY   0.5f
#define VTH     1.0f

typedef float f32x4 __attribute__((ext_vector_type(4)));

__device__ __forceinline__ f32x4 lif_step(f32x4& v, f32x4 xv) {
    v = v * DECAY + xv;                      // elementwise leak + integrate
    f32x4 s;
    s.x = (v.x >= VTH) ? 1.f : 0.f;
    s.y = (v.y >= VTH) ? 1.f : 0.f;
    s.z = (v.z >= VTH) ? 1.f : 0.f;
    s.w = (v.w >= VTH) ? 1.f : 0.f;
    v = v - s * VTH;                         // soft reset
    return s;
}

__global__ __launch_bounds__(256) void lif_kernel(
    const f32x4* __restrict__ x, f32x4* __restrict__ out, int f4_per_row) {
    int f = blockIdx.x * blockDim.x + threadIdx.x;   // float4 column
    int n = blockIdx.y;                              // neuron index

    size_t base = ((size_t)n * T_STEPS) * f4_per_row + f;
    const f32x4* xp = x + base;
    f32x4*       op = out + base;

    // Hoist all 4 loads: 64 B in flight per thread before any compute.
    f32x4 x0 = xp[(size_t)0 * f4_per_row];
    f32x4 x1 = xp[(size_t)1 * f4_per_row];
    f32x4 x2 = xp[(size_t)2 * f4_per_row];
    f32x4 x3 = xp[(size_t)3 * f4_per_row];

    f32x4 v = (f32x4)(0.f);
    f32x4 s0 = lif_step(v, x0);
    f32x4 s1 = lif_step(v, x1);
    f32x4 s2 = lif_step(v, x2);
    f32x4 s3 = lif_step(v, x3);

    __builtin_nontemporal_store(s0, op + (size_t)0 * f4_per_row);
    __builtin_nontemporal_store(s1, op + (size_t)1 * f4_per_row);
    __builtin_nontemporal_store(s2, op + (size_t)2 * f4_per_row);
    __builtin_nontemporal_store(s3, op + (size_t)3 * f4_per_row);
}

extern "C" void kernel_launch(void* const* d_in, const int* in_sizes, int n_in,
                              void* d_out, int out_size, void* d_ws, size_t ws_size,
                              hipStream_t stream) {
    const float* x = (const float*)d_in[0];
    float* out = (float*)d_out;

    const int B = 256;                 // N*T rows
    const int F = in_sizes[0] / B;     // 65536
    const int N = B / T_STEPS;         // 64
    const int F4 = F / 4;              // 16384 float4 per row

    dim3 block(256);
    dim3 grid(F4 / 256, N);            // (64, 64) blocks

    lif_kernel<<<grid, block, 0, stream>>>(
        (const f32x4*)x, (f32x4*)out, F4);
}